// Round 10
// baseline (6444.827 us; speedup 1.0000x reference)
//
#include <hip/hip_runtime.h>

// Problem constants (fixed by reference setup)
#define B_ 32
#define T_ 8192
#define I_ 16
#define H_ 128
#define P_ 1024
#define O_ 3

typedef _Float16 h2 __attribute__((ext_vector_type(2)));
typedef _Float16 h4 __attribute__((ext_vector_type(4)));
typedef _Float16 h8 __attribute__((ext_vector_type(8)));

// v_dot2_f32_f16: 2-way f16 dot, fp32 accumulate (CDNA dot insts)
#if __has_builtin(__builtin_amdgcn_fdot2)
#define FDOT2(a, b, c) __builtin_amdgcn_fdot2((a), (b), (c), false)
#else
__device__ __forceinline__ float fdot2_asm(h2 a, h2 b, float c) {
    asm("v_dot2_f32_f16 %0, %1, %2, %0" : "+v"(c) : "v"(a), "v"(b));
    return c;
}
#define FDOT2(a, b, c) fdot2_asm((a), (b), (c))
#endif

// ---- macro machinery: (gate g 0..3, m 0..3, e 0..3) ------------------------
#define FORME(M, g) M(g,0,0) M(g,0,1) M(g,0,2) M(g,0,3) \
                    M(g,1,0) M(g,1,1) M(g,1,2) M(g,1,3) \
                    M(g,2,0) M(g,2,1) M(g,2,2) M(g,2,3) \
                    M(g,3,0) M(g,3,1) M(g,3,2) M(g,3,3)
#define FORALL(M) FORME(M,0) FORME(M,1) FORME(M,2) FORME(M,3)
#define FORG(M) M(0) M(1) M(2) M(3)

// DPP (quad_perm / row_ror): pure-VALU cross-lane, no LDS round-trip.
// (GCNDPPCombine fuses mov_dpp + single-use add into v_add_f32_dpp.)
#define DPPF(v, ctrl) \
    __int_as_float(__builtin_amdgcn_mov_dpp(__float_as_int(v), (ctrl), 0xF, 0xF, true))

// xor32-add via gfx950 v_permlane32_swap_b32 (pure VALU).
__device__ __forceinline__ float xor32_add(float p) {
    float a = p, b = p;
    asm("v_permlane32_swap_b32 %0, %1" : "+v"(a), "+v"(b));
    return a + b;
}

__device__ __forceinline__ float tanh_f(float x) {
    return 2.f / (1.f + __expf(-2.f * x)) - 1.f;
}
__device__ __forceinline__ h4 cvt4(float4 v) {
    return (h4){(_Float16)v.x, (_Float16)v.y, (_Float16)v.z, (_Float16)v.w};
}

// LDS-only barrier: drain DS ops + s_barrier, without __syncthreads' vmcnt(0)
// drain (x-prefetch loads are consumed via register dependency).
__device__ __forceinline__ void lds_barrier() {
    asm volatile("s_waitcnt lgkmcnt(0)\n\ts_barrier" ::: "memory");
}

// R15: latency-chain trim on the proven R6 base (6055 us). Evidence: R13 at
// 92% per-active-CU VALUBusy was SLOWER than R6 at 69% -> the step is bound
// by the serial chain (dsread ~120 + 18-deep dot chain ~144 + 2 exp chains
// + write/barrier), not by issue. Changes vs R6 (everything else identical):
//  (1) acc chains split 2-way (9-10 deep halves + 1 merge add): ~-60cy chain;
//  (2) all 5 LDS reads hoisted to the top of the body, before the atomics,
//      so the h/x read latency starts immediately at barrier release;
//  (3) lane-constant activation folding (aSc/mA/aB replace 2 cndmask sels).
__global__ __launch_bounds__(512, 2) __attribute__((amdgpu_waves_per_eu(2, 2)))
void lstm_fused(
    const float* __restrict__ x,      // [B,T,16]
    const float* __restrict__ W_ih,   // [512,16]
    const float* __restrict__ W_hh,   // [512,128]
    const float* __restrict__ b_ih,   // [512]
    const float* __restrict__ b_hh,   // [512]
    const float* __restrict__ W_fc,   // [3,128]
    float* __restrict__ sums,         // [B,P,3]  (fully overwritten per block)
    float* __restrict__ counts)       // [B,P]    (fully overwritten per block)
{
    const int b   = blockIdx.x;
    const int tid = threadIdx.x;
    const int j   = tid >> 2;
    const int kc  = tid & 3;

    __shared__ __align__(16) _Float16 hh[2][H_];       // hidden state, f16
    __shared__ __align__(16) _Float16 xt[2][16 * I_];  // x tile, f16
    __shared__ float sums_lds[P_ * O_];                // 12 KB
    __shared__ float counts_lds[P_];                   // 4 KB

    // ---- weights -> f16 half2 named scalars (64 + 8 = 72 VGPRs) ----
    const float* wr0 = W_hh + (0 * H_ + j) * H_;
    const float* wr1 = W_hh + (1 * H_ + j) * H_;
    const float* wr2 = W_hh + (2 * H_ + j) * H_;
    const float* wr3 = W_hh + (3 * H_ + j) * H_;
    // slot (g,m,e) holds W_hh[g*128+j][kc*8+32m+2e .. +1]
    #define WLOAD(g, m, e) h2 W##g##_##m##_##e = (h2){ \
        (_Float16)wr##g[kc * 8 + 32 * (m) + 2 * (e)], \
        (_Float16)wr##g[kc * 8 + 32 * (m) + 2 * (e) + 1]};
    FORALL(WLOAD)

    // W_ih: gate g, x-chunk [kc*4, kc*4+4) as 2 half2
    #define ULOAD(g) \
        h2 U##g##_0 = (h2){(_Float16)W_ih[((g) * H_ + j) * I_ + kc * 4 + 0], \
                           (_Float16)W_ih[((g) * H_ + j) * I_ + kc * 4 + 1]}; \
        h2 U##g##_1 = (h2){(_Float16)W_ih[((g) * H_ + j) * I_ + kc * 4 + 2], \
                           (_Float16)W_ih[((g) * H_ + j) * I_ + kc * 4 + 3]};
    FORG(ULOAD)

    // lane kc activates gate kc: its own row is kc*128+j
    const float bias = b_ih[kc * H_ + j] + b_hh[kc * H_ + j];
    const float wfc  = (kc < 3) ? W_fc[kc * H_ + j] : 0.f;
    // lane-constant activation folding: i,f,o: sig(x); g (kc==2): tanh(x) =
    // 2*sig(2x)-1. arg = tg*aSc; act = sf*mA + aB.
    const float aSc = (kc == 2) ? 2.f : 1.f;
    const float mA  = (kc == 2) ? 2.f : 1.f;
    const float aB  = (kc == 2) ? -1.f : 0.f;

    // FC atomic lanes: reduce covers lane-xor {4,8,32} (row_ror x2 +
    // permlane32); remaining xor16 handled by 2-way same-address atomic from
    // lanes {kc, 16+kc}. Mask bits 2,3,5 of the lane id.
    const bool fc_lane = ((tid & 0x2C) == 0) && (kc < 3);

    // ---- init LDS ----
    for (int i = tid; i < P_ * O_; i += 512) sums_lds[i] = 0.f;
    for (int i = tid; i < P_;      i += 512) counts_lds[i] = 0.f;
    if (tid < H_) hh[0][tid] = (_Float16)0.f;

    const float* xb = x + (size_t)b * T_ * I_;
    float4 xr4 = make_float4(0.f, 0.f, 0.f, 0.f);
    if (tid < 64) {                       // tile 0 = steps 0..15
        xr4 = ((const float4*)xb)[tid];
        *(h4*)&xt[0][tid * 4] = cvt4(xr4);
    }
    float c = 0.f;
    float pend_p = 0.f;   // pipelined FC partial (from step t-1)
    int   pend_id = 0;
    __syncthreads();

    #pragma unroll 1
    for (int t = 0; t < T_; ++t) {
        const int off = t & 15;
        const int btx = (t >> 4) & 1;
        const int bh  = t & 1;

        // ---- LDS reads FIRST: h/x read latency starts at barrier release;
        // atomics/prefetch below ride under it.
        const h8 hv0 = *(const h8*)&hh[bh][kc * 8 +  0];
        const h8 hv1 = *(const h8*)&hh[bh][kc * 8 + 32];
        const h8 hv2 = *(const h8*)&hh[bh][kc * 8 + 64];
        const h8 hv3 = *(const h8*)&hh[bh][kc * 8 + 96];
        const h4 xv4 = *(const h4*)&xt[btx][off * I_ + kc * 4];
        const int id = (int)(float)xt[btx][off * I_ + 2];   // exact (id<2048)

        // ---- pipelined FC/count atomics from step t-1 (off the critical
        // path: complete during the dot phase, long done by the barrier).
        if (t != 0) {
            if (fc_lane && (unsigned)pend_id < (unsigned)P_)
                atomicAdd(&sums_lds[pend_id * O_ + kc], pend_p);
            if (tid == 0 && (unsigned)pend_id < (unsigned)P_)
                atomicAdd(&counts_lds[pend_id], 1.f);
        }

        // x prefetch (wave 0): issue tile t+16 at off==0, commit at off==8
        if (tid < 64) {
            if (off == 0 && t + 16 < T_)
                xr4 = ((const float4*)(xb + (t + 16) * I_))[tid];
            if (off == 8 && t + 8 < T_)
                *(h4*)&xt[btx ^ 1][tid * 4] = cvt4(xr4);
        }

        const h2 xv0 = __builtin_shufflevector(xv4, xv4, 0, 1);
        const h2 xv1 = __builtin_shufflevector(xv4, xv4, 2, 3);

        // 4 gate-row partials over this thread's 32-float h subset, each as
        // TWO independent 8-10-deep chains (halved dep latency), merged once.
        float a0a = 0.f, a1a = 0.f, a2a = 0.f, a3a = 0.f;
        float a0b = 0.f, a1b = 0.f, a2b = 0.f, a3b = 0.f;
        #define HD(m, s, hvn) { \
            h2 p0 = __builtin_shufflevector(hvn, hvn, 0, 1); \
            h2 p1 = __builtin_shufflevector(hvn, hvn, 2, 3); \
            h2 p2 = __builtin_shufflevector(hvn, hvn, 4, 5); \
            h2 p3 = __builtin_shufflevector(hvn, hvn, 6, 7); \
            a0##s = FDOT2(p0, W0_##m##_0, a0##s); a0##s = FDOT2(p1, W0_##m##_1, a0##s); \
            a0##s = FDOT2(p2, W0_##m##_2, a0##s); a0##s = FDOT2(p3, W0_##m##_3, a0##s); \
            a1##s = FDOT2(p0, W1_##m##_0, a1##s); a1##s = FDOT2(p1, W1_##m##_1, a1##s); \
            a1##s = FDOT2(p2, W1_##m##_2, a1##s); a1##s = FDOT2(p3, W1_##m##_3, a1##s); \
            a2##s = FDOT2(p0, W2_##m##_0, a2##s); a2##s = FDOT2(p1, W2_##m##_1, a2##s); \
            a2##s = FDOT2(p2, W2_##m##_2, a2##s); a2##s = FDOT2(p3, W2_##m##_3, a2##s); \
            a3##s = FDOT2(p0, W3_##m##_0, a3##s); a3##s = FDOT2(p1, W3_##m##_1, a3##s); \
            a3##s = FDOT2(p2, W3_##m##_2, a3##s); a3##s = FDOT2(p3, W3_##m##_3, a3##s); }
        HD(0, a, hv0) HD(1, a, hv1)
        HD(2, b, hv2) HD(3, b, hv3)
        // x contribution -> the 'a' chains (balances depth: a=10, b=8)
        a0a = FDOT2(xv0, U0_0, a0a); a0a = FDOT2(xv1, U0_1, a0a);
        a1a = FDOT2(xv0, U1_0, a1a); a1a = FDOT2(xv1, U1_1, a1a);
        a2a = FDOT2(xv0, U2_0, a2a); a2a = FDOT2(xv1, U2_1, a2a);
        a3a = FDOT2(xv0, U3_0, a3a); a3a = FDOT2(xv1, U3_1, a3a);

        float acc0 = a0a + a0b;
        float acc1 = a1a + a1b;
        float acc2 = a2a + a2b;
        float acc3 = a3a + a3b;

        // quad butterfly (xor1=0xB1, xor2=0x4E): all 4 lanes get all 4 totals
        float s_;
        s_ = DPPF(acc0, 0xB1); acc0 += s_;
        s_ = DPPF(acc1, 0xB1); acc1 += s_;
        s_ = DPPF(acc2, 0xB1); acc2 += s_;
        s_ = DPPF(acc3, 0xB1); acc3 += s_;
        s_ = DPPF(acc0, 0x4E); acc0 += s_;
        s_ = DPPF(acc1, 0x4E); acc1 += s_;
        s_ = DPPF(acc2, 0x4E); acc2 += s_;
        s_ = DPPF(acc3, 0x4E); acc3 += s_;

        // lane kc activates gate kc (lane-const folded sigmoid/tanh)
        float tg = (kc == 0) ? acc0 : (kc == 1) ? acc1 : (kc == 2) ? acc2 : acc3;
        tg += bias;
        const float sf  = 1.f / (1.f + __expf(-tg * aSc));
        const float act = fmaf(sf, mA, aB);

        // gather the quad's 4 activated gates (quad_perm broadcasts)
        const float gi = DPPF(act, 0x00);
        const float gf = DPPF(act, 0x55);
        const float gg = DPPF(act, 0xAA);
        const float go = DPPF(act, 0xFF);
        c = fmaf(gf, c, gi * gg);            // c replicated across the quad (fp32)
        const float hnew = go * tanh_f(c);

        if (kc == 0) hh[bh ^ 1][j] = (_Float16)hnew;   // publish h_t (f16)

        // fused FC partial: VALU-only wave reduce (row_ror:4 + row_ror:8 +
        // permlane32_swap); xor16 left for the 2-way same-address atomic.
        float p = hnew * wfc;
        p += DPPF(p, 0x124);
        p += DPPF(p, 0x128);
        p = xor32_add(p);
        pend_p  = p;
        pend_id = id;

        lds_barrier();   // single barrier per step (h double-buffered)
    }

    // flush the final step's pipelined contribution
    if (fc_lane && (unsigned)pend_id < (unsigned)P_)
        atomicAdd(&sums_lds[pend_id * O_ + kc], pend_p);
    if (tid == 0 && (unsigned)pend_id < (unsigned)P_)
        atomicAdd(&counts_lds[pend_id], 1.f);
    __syncthreads();

    // ---- writeback (block b owns slice b exclusively) ----
    float* sums_g = sums + (size_t)b * P_ * O_;
    for (int i = tid; i < P_ * O_; i += 512) sums_g[i] = sums_lds[i];
    float* cnt_g = counts + (size_t)b * P_;
    for (int i = tid; i < P_; i += 512) cnt_g[i] = counts_lds[i];
}

// out[b,p,o] = (sums[b,p,o] + cnt*b_fc[o]) / max(cnt,1)
__global__ void finalize_kernel(const float* __restrict__ sums,
                                const float* __restrict__ counts,
                                const float* __restrict__ b_fc,
                                float* __restrict__ out)
{
    const int idx = blockIdx.x * blockDim.x + threadIdx.x;
    if (idx >= B_ * P_ * O_) return;
    const int o  = idx % O_;
    const int bp = idx / O_;
    const float cnt = counts[bp];
    const float denom = (cnt > 0.f) ? cnt : 1.f;
    out[idx] = (sums[idx] + cnt * b_fc[o]) / denom;
}

extern "C" void kernel_launch(void* const* d_in, const int* in_sizes, int n_in,
                              void* d_out, int out_size, void* d_ws, size_t ws_size,
                              hipStream_t stream) {
    const float* x    = (const float*)d_in[0];
    const float* W_ih = (const float*)d_in[1];
    const float* W_hh = (const float*)d_in[2];
    const float* b_ih = (const float*)d_in[3];
    const float* b_hh = (const float*)d_in[4];
    const float* W_fc = (const float*)d_in[5];
    const float* b_fc = (const float*)d_in[6];
    // d_in[7] = num_photos (==P_, fixed by the problem)

    float* out    = (float*)d_out;
    float* sums   = (float*)d_ws;                 // B*P*3 floats
    float* counts = sums + (size_t)B_ * P_ * O_;  // B*P floats
    // sums/counts fully overwritten by lstm_fused — no memset needed.

    lstm_fused<<<B_, 512, 0, stream>>>(x, W_ih, W_hh, b_ih, b_hh, W_fc,
                                       sums, counts);

    const int n = B_ * P_ * O_;
    finalize_kernel<<<(n + 255) / 256, 256, 0, stream>>>(sums, counts, b_fc, out);
}

// Round 11
// 6112.938 us; speedup vs baseline: 1.0543x; 1.0543x over previous
//
#include <hip/hip_runtime.h>

// Problem constants (fixed by reference setup)
#define B_ 32
#define T_ 8192
#define I_ 16
#define H_ 128
#define P_ 1024
#define O_ 3
#define R_ 512     // 4*H gate rows

typedef _Float16 h2 __attribute__((ext_vector_type(2)));
typedef _Float16 h4 __attribute__((ext_vector_type(4)));
typedef _Float16 h8 __attribute__((ext_vector_type(8)));
typedef unsigned short u16;

// v_dot2_f32_f16: 2-way f16 dot, fp32 accumulate
#if __has_builtin(__builtin_amdgcn_fdot2)
#define FDOT2(a, b, c) __builtin_amdgcn_fdot2((a), (b), (c), false)
#else
__device__ __forceinline__ float fdot2_asm(h2 a, h2 b, float c) {
    asm("v_dot2_f32_f16 %0, %1, %2, %0" : "+v"(c) : "v"(a), "v"(b));
    return c;
}
#define FDOT2(a, b, c) fdot2_asm((a), (b), (c))
#endif

// ---- macro machinery: (gate g 0..3, m 0..3, e 0..3) ------------------------
#define FORME(M, g) M(g,0,0) M(g,0,1) M(g,0,2) M(g,0,3) \
                    M(g,1,0) M(g,1,1) M(g,1,2) M(g,1,3) \
                    M(g,2,0) M(g,2,1) M(g,2,2) M(g,2,3) \
                    M(g,3,0) M(g,3,1) M(g,3,2) M(g,3,3)
#define FORALL(M) FORME(M,0) FORME(M,1) FORME(M,2) FORME(M,3)
#define FORG(M) M(0) M(1) M(2) M(3)

#define DPPF(v, ctrl) \
    __int_as_float(__builtin_amdgcn_mov_dpp(__float_as_int(v), (ctrl), 0xF, 0xF, true))

__device__ __forceinline__ float xor32_add(float p) {
    float a = p, b = p;
    asm("v_permlane32_swap_b32 %0, %1" : "+v"(a), "+v"(b));
    return a + b;
}

__device__ __forceinline__ float tanh_f(float x) {
    return 2.f / (1.f + __expf(-2.f * x)) - 1.f;
}
__device__ __forceinline__ h4 cvt4(float4 v) {
    return (h4){(_Float16)v.x, (_Float16)v.y, (_Float16)v.z, (_Float16)v.w};
}
__device__ __forceinline__ void lds_barrier() {
    asm volatile("s_waitcnt lgkmcnt(0)\n\ts_barrier" ::: "memory");
}

// ============================================================================
// R16: the x-path (W_ih*x + biases, id extraction) is NOT part of the
// sequential dependency — precompute it for all (b,t) in a parallel kernel
// (xg[b][row][t] f16, bias-folded; ids[b][t] u16) and strip it from the
// recurrence: -8 dot2, -xt staging, -wave0 prefetch, -bias add per step.
// Model basis (R13/R14/R15): step = ~1176cy VALU issue + ~580cy latency;
// only instruction REMOVAL moves it. Workspace 257MB guarded by ws_size,
// verbatim fallback kernel otherwise.
// ============================================================================

__global__ __launch_bounds__(256)
void xg_precompute(
    const float* __restrict__ x,      // [B,T,16]
    const float* __restrict__ W_ih,   // [512,16]
    const float* __restrict__ b_ih,   // [512]
    const float* __restrict__ b_hh,   // [512]
    _Float16* __restrict__ xg,        // [B][512][T]
    u16* __restrict__ ids)            // [B][T]
{
    const int nchunk = T_ / 64;               // 128 chunks per batch
    const int b   = blockIdx.x / nchunk;
    const int t0  = (blockIdx.x % nchunk) * 64;
    const int tid = threadIdx.x;

    __shared__ __align__(16) float xs[64][I_];   // 4 KB x tile

    // cooperative tile load: 1024 floats = 256 x float4, coalesced
    ((float4*)xs)[tid] = ((const float4*)(x + ((size_t)b * T_ + t0) * I_))[tid];
    __syncthreads();
    if (tid < 64)
        ids[(size_t)b * T_ + t0 + tid] = (u16)(int)xs[tid][2];

    // thread handles rows {2*tid, 2*tid+1} for all 64 timesteps
    const int r0 = tid * 2;
    float w0[I_], w1[I_];
    #pragma unroll
    for (int i = 0; i < I_; ++i) {
        w0[i] = W_ih[r0 * I_ + i];
        w1[i] = W_ih[(r0 + 1) * I_ + i];
    }
    const float bb0 = b_ih[r0] + b_hh[r0];
    const float bb1 = b_ih[r0 + 1] + b_hh[r0 + 1];

    _Float16* o0 = xg + ((size_t)b * R_ + r0) * T_ + t0;
    _Float16* o1 = o0 + T_;
    #pragma unroll 1
    for (int cc = 0; cc < 8; ++cc) {
        h8 v0, v1;
        #pragma unroll
        for (int kk = 0; kk < 8; ++kk) {
            const float* xr = xs[cc * 8 + kk];
            float a0 = bb0, a1 = bb1;
            #pragma unroll
            for (int i2 = 0; i2 < I_; ++i2) {
                a0 = fmaf(w0[i2], xr[i2], a0);
                a1 = fmaf(w1[i2], xr[i2], a1);
            }
            v0[kk] = (_Float16)a0;
            v1[kk] = (_Float16)a1;
        }
        *(h8*)&o0[cc * 8] = v0;    // 16B-aligned (t0 mult of 64)
        *(h8*)&o1[cc * 8] = v1;
    }
}

// Sequential kernel, xg-fed. Structure = proven Round-0 512-thread base:
// thread (j=tid>>2, kc=tid&3), 72->64 dot2, quad butterfly, single
// lds_barrier/step, VALU FC reduce, atomics pipelined one step. Inner loop
// unrolled 8x so the prefetched h8/uint4 buffers index statically (rule:
// runtime-indexed ext_vector goes to scratch).
__global__ __launch_bounds__(512, 2) __attribute__((amdgpu_waves_per_eu(2, 2)))
void lstm_fused_xg(
    const _Float16* __restrict__ xg,  // [B][512][T], bias-folded
    const u16* __restrict__ ids,      // [B][T]
    const float* __restrict__ W_hh,   // [512,128]
    const float* __restrict__ W_fc,   // [3,128]
    float* __restrict__ sums,         // [B,P,3]
    float* __restrict__ counts)       // [B,P]
{
    const int b   = blockIdx.x;
    const int tid = threadIdx.x;
    const int j   = tid >> 2;
    const int kc  = tid & 3;

    __shared__ __align__(16) _Float16 hh[2][H_];
    __shared__ float sums_lds[P_ * O_];
    __shared__ float counts_lds[P_];

    // weights -> f16 half2 named scalars (64 VGPRs)
    const float* wr0 = W_hh + (0 * H_ + j) * H_;
    const float* wr1 = W_hh + (1 * H_ + j) * H_;
    const float* wr2 = W_hh + (2 * H_ + j) * H_;
    const float* wr3 = W_hh + (3 * H_ + j) * H_;
    #define WLOAD(g, m, e) h2 W##g##_##m##_##e = (h2){ \
        (_Float16)wr##g[kc * 8 + 32 * (m) + 2 * (e)], \
        (_Float16)wr##g[kc * 8 + 32 * (m) + 2 * (e) + 1]};
    FORALL(WLOAD)

    const float wfc = (kc < 3) ? W_fc[kc * H_ + j] : 0.f;
    const bool fc_lane = ((tid & 0x2C) == 0) && (kc < 3);

    for (int i = tid; i < P_ * O_; i += 512) sums_lds[i] = 0.f;
    for (int i = tid; i < P_;      i += 512) counts_lds[i] = 0.f;
    if (tid < H_) hh[0][tid] = (_Float16)0.f;

    // per-lane xg stream (this lane's gate row), id stream (per batch)
    const _Float16* xgp = xg + ((size_t)b * R_ + kc * H_ + j) * T_;
    const u16*      idp = ids + (size_t)b * T_;

    h8    xc  = *(const h8*)&xgp[0];     // steps [0,8)
    h8    xn  = *(const h8*)&xgp[8];     // steps [8,16)
    uint4 idc = *(const uint4*)&idp[0];
    uint4 idn = *(const uint4*)&idp[8];

    float c = 0.f;
    float pend_p = 0.f;
    int   pend_id = 0;
    __syncthreads();

    #pragma unroll 1
    for (int tt = 0; tt < T_; tt += 8) {
        #pragma unroll
        for (int k = 0; k < 8; ++k) {
            const int bh = k & 1;    // static per unrolled step (tt even)

            // pipelined FC/count atomics from step t-1
            if (k != 0 || tt != 0) {
                if (fc_lane && (unsigned)pend_id < (unsigned)P_)
                    atomicAdd(&sums_lds[pend_id * O_ + kc], pend_p);
                if (tid == 0 && (unsigned)pend_id < (unsigned)P_)
                    atomicAdd(&counts_lds[pend_id], 1.f);
            }

            // 4 gate-row partials over this thread's 32-elem h slice
            float acc0 = 0.f, acc1 = 0.f, acc2 = 0.f, acc3 = 0.f;
            #define HD(m) { \
                h8 hv = *(const h8*)&hh[bh][kc * 8 + 32 * (m)]; \
                h2 p0 = __builtin_shufflevector(hv, hv, 0, 1); \
                h2 p1 = __builtin_shufflevector(hv, hv, 2, 3); \
                h2 p2 = __builtin_shufflevector(hv, hv, 4, 5); \
                h2 p3 = __builtin_shufflevector(hv, hv, 6, 7); \
                acc0 = FDOT2(p0, W0_##m##_0, acc0); acc0 = FDOT2(p1, W0_##m##_1, acc0); \
                acc0 = FDOT2(p2, W0_##m##_2, acc0); acc0 = FDOT2(p3, W0_##m##_3, acc0); \
                acc1 = FDOT2(p0, W1_##m##_0, acc1); acc1 = FDOT2(p1, W1_##m##_1, acc1); \
                acc1 = FDOT2(p2, W1_##m##_2, acc1); acc1 = FDOT2(p3, W1_##m##_3, acc1); \
                acc2 = FDOT2(p0, W2_##m##_0, acc2); acc2 = FDOT2(p1, W2_##m##_1, acc2); \
                acc2 = FDOT2(p2, W2_##m##_2, acc2); acc2 = FDOT2(p3, W2_##m##_3, acc2); \
                acc3 = FDOT2(p0, W3_##m##_0, acc3); acc3 = FDOT2(p1, W3_##m##_1, acc3); \
                acc3 = FDOT2(p2, W3_##m##_2, acc3); acc3 = FDOT2(p3, W3_##m##_3, acc3); }
            HD(0) HD(1) HD(2) HD(3)
            #undef HD

            // quad butterfly: all 4 lanes get all 4 gate totals
            float s_;
            s_ = DPPF(acc0, 0xB1); acc0 += s_;
            s_ = DPPF(acc1, 0xB1); acc1 += s_;
            s_ = DPPF(acc2, 0xB1); acc2 += s_;
            s_ = DPPF(acc3, 0xB1); acc3 += s_;
            s_ = DPPF(acc0, 0x4E); acc0 += s_;
            s_ = DPPF(acc1, 0x4E); acc1 += s_;
            s_ = DPPF(acc2, 0x4E); acc2 += s_;
            s_ = DPPF(acc3, 0x4E); acc3 += s_;

            // lane kc activates gate kc; xg term (bias-folded) replaces bias
            float tg = (kc == 0) ? acc0 : (kc == 1) ? acc1 : (kc == 2) ? acc2 : acc3;
            tg += (float)xc[k];
            const bool  isg = (kc == 2);
            const float arg = isg ? (tg + tg) : tg;
            const float sf  = 1.f / (1.f + __expf(-arg));
            const float act = isg ? (sf + sf - 1.f) : sf;

            const float gi = DPPF(act, 0x00);
            const float gf = DPPF(act, 0x55);
            const float gg = DPPF(act, 0xAA);
            const float go = DPPF(act, 0xFF);
            c = fmaf(gf, c, gi * gg);
            const float hnew = go * tanh_f(c);

            if (kc == 0) hh[bh ^ 1][j] = (_Float16)hnew;

            // fused FC partial: VALU-only reduce, atomics deferred one step
            float p = hnew * wfc;
            p += DPPF(p, 0x124);
            p += DPPF(p, 0x128);
            p = xor32_add(p);
            pend_p = p;
            const unsigned idw = (k < 2) ? idc.x : (k < 4) ? idc.y
                               : (k < 6) ? idc.z : idc.w;      // folds (k static)
            pend_id = (int)((idw >> ((k & 1) * 16)) & 0xffffu);

            lds_barrier();
        }
        // rotate prefetch buffers; issue next chunk (8-step distance)
        xc = xn; idc = idn;
        if (tt + 16 < T_) {
            xn  = *(const h8*)&xgp[tt + 16];
            idn = *(const uint4*)&idp[tt + 16];
        }
    }

    if (fc_lane && (unsigned)pend_id < (unsigned)P_)
        atomicAdd(&sums_lds[pend_id * O_ + kc], pend_p);
    if (tid == 0 && (unsigned)pend_id < (unsigned)P_)
        atomicAdd(&counts_lds[pend_id], 1.f);
    __syncthreads();

    float* sums_g = sums + (size_t)b * P_ * O_;
    for (int i = tid; i < P_ * O_; i += 512) sums_g[i] = sums_lds[i];
    float* cnt_g = counts + (size_t)b * P_;
    for (int i = tid; i < P_; i += 512) cnt_g[i] = counts_lds[i];
}

// ============================================================================
// Fallback (verbatim passing Round-0 kernel) — used when ws too small for xg.
// ============================================================================
__global__ __launch_bounds__(512, 2) __attribute__((amdgpu_waves_per_eu(2, 2)))
void lstm_fused_fb(
    const float* __restrict__ x, const float* __restrict__ W_ih,
    const float* __restrict__ W_hh, const float* __restrict__ b_ih,
    const float* __restrict__ b_hh, const float* __restrict__ W_fc,
    float* __restrict__ sums, float* __restrict__ counts)
{
    const int b   = blockIdx.x;
    const int tid = threadIdx.x;
    const int j   = tid >> 2;
    const int kc  = tid & 3;

    __shared__ __align__(16) _Float16 hh[2][H_];
    __shared__ __align__(16) _Float16 xt[2][16 * I_];
    __shared__ float sums_lds[P_ * O_];
    __shared__ float counts_lds[P_];

    const float* wr0 = W_hh + (0 * H_ + j) * H_;
    const float* wr1 = W_hh + (1 * H_ + j) * H_;
    const float* wr2 = W_hh + (2 * H_ + j) * H_;
    const float* wr3 = W_hh + (3 * H_ + j) * H_;
    #define WLOADF(g, m, e) h2 W##g##_##m##_##e = (h2){ \
        (_Float16)wr##g[kc * 8 + 32 * (m) + 2 * (e)], \
        (_Float16)wr##g[kc * 8 + 32 * (m) + 2 * (e) + 1]};
    FORALL(WLOADF)

    #define ULOAD(g) \
        h2 U##g##_0 = (h2){(_Float16)W_ih[((g) * H_ + j) * I_ + kc * 4 + 0], \
                           (_Float16)W_ih[((g) * H_ + j) * I_ + kc * 4 + 1]}; \
        h2 U##g##_1 = (h2){(_Float16)W_ih[((g) * H_ + j) * I_ + kc * 4 + 2], \
                           (_Float16)W_ih[((g) * H_ + j) * I_ + kc * 4 + 3]};
    FORG(ULOAD)

    const float bias = b_ih[kc * H_ + j] + b_hh[kc * H_ + j];
    const float wfc  = (kc < 3) ? W_fc[kc * H_ + j] : 0.f;
    const bool fc_lane = ((tid & 0x2C) == 0) && (kc < 3);

    for (int i = tid; i < P_ * O_; i += 512) sums_lds[i] = 0.f;
    for (int i = tid; i < P_;      i += 512) counts_lds[i] = 0.f;
    if (tid < H_) hh[0][tid] = (_Float16)0.f;

    const float* xb = x + (size_t)b * T_ * I_;
    float4 xr4 = make_float4(0.f, 0.f, 0.f, 0.f);
    if (tid < 64) {
        xr4 = ((const float4*)xb)[tid];
        *(h4*)&xt[0][tid * 4] = cvt4(xr4);
    }
    float c = 0.f;
    float pend_p = 0.f;
    int   pend_id = 0;
    __syncthreads();

    #pragma unroll 1
    for (int t = 0; t < T_; ++t) {
        const int off = t & 15;
        const int btx = (t >> 4) & 1;
        const int bh  = t & 1;

        if (t != 0) {
            if (fc_lane && (unsigned)pend_id < (unsigned)P_)
                atomicAdd(&sums_lds[pend_id * O_ + kc], pend_p);
            if (tid == 0 && (unsigned)pend_id < (unsigned)P_)
                atomicAdd(&counts_lds[pend_id], 1.f);
        }

        if (tid < 64) {
            if (off == 0 && t + 16 < T_)
                xr4 = ((const float4*)(xb + (t + 16) * I_))[tid];
            if (off == 8 && t + 8 < T_)
                *(h4*)&xt[btx ^ 1][tid * 4] = cvt4(xr4);
        }

        const h4 xv4 = *(const h4*)&xt[btx][off * I_ + kc * 4];
        const h2 xv0 = __builtin_shufflevector(xv4, xv4, 0, 1);
        const h2 xv1 = __builtin_shufflevector(xv4, xv4, 2, 3);
        const int id = (int)(float)xt[btx][off * I_ + 2];

        float acc0 = 0.f, acc1 = 0.f, acc2 = 0.f, acc3 = 0.f;
        #define HDF(m) { \
            h8 hv = *(const h8*)&hh[bh][kc * 8 + 32 * (m)]; \
            h2 p0 = __builtin_shufflevector(hv, hv, 0, 1); \
            h2 p1 = __builtin_shufflevector(hv, hv, 2, 3); \
            h2 p2 = __builtin_shufflevector(hv, hv, 4, 5); \
            h2 p3 = __builtin_shufflevector(hv, hv, 6, 7); \
            acc0 = FDOT2(p0, W0_##m##_0, acc0); acc0 = FDOT2(p1, W0_##m##_1, acc0); \
            acc0 = FDOT2(p2, W0_##m##_2, acc0); acc0 = FDOT2(p3, W0_##m##_3, acc0); \
            acc1 = FDOT2(p0, W1_##m##_0, acc1); acc1 = FDOT2(p1, W1_##m##_1, acc1); \
            acc1 = FDOT2(p2, W1_##m##_2, acc1); acc1 = FDOT2(p3, W1_##m##_3, acc1); \
            acc2 = FDOT2(p0, W2_##m##_0, acc2); acc2 = FDOT2(p1, W2_##m##_1, acc2); \
            acc2 = FDOT2(p2, W2_##m##_2, acc2); acc2 = FDOT2(p3, W2_##m##_3, acc2); \
            acc3 = FDOT2(p0, W3_##m##_0, acc3); acc3 = FDOT2(p1, W3_##m##_1, acc3); \
            acc3 = FDOT2(p2, W3_##m##_2, acc3); acc3 = FDOT2(p3, W3_##m##_3, acc3); }
        HDF(0) HDF(1) HDF(2) HDF(3)
        acc0 = FDOT2(xv0, U0_0, acc0); acc0 = FDOT2(xv1, U0_1, acc0);
        acc1 = FDOT2(xv0, U1_0, acc1); acc1 = FDOT2(xv1, U1_1, acc1);
        acc2 = FDOT2(xv0, U2_0, acc2); acc2 = FDOT2(xv1, U2_1, acc2);
        acc3 = FDOT2(xv0, U3_0, acc3); acc3 = FDOT2(xv1, U3_1, acc3);

        float s_;
        s_ = DPPF(acc0, 0xB1); acc0 += s_;
        s_ = DPPF(acc1, 0xB1); acc1 += s_;
        s_ = DPPF(acc2, 0xB1); acc2 += s_;
        s_ = DPPF(acc3, 0xB1); acc3 += s_;
        s_ = DPPF(acc0, 0x4E); acc0 += s_;
        s_ = DPPF(acc1, 0x4E); acc1 += s_;
        s_ = DPPF(acc2, 0x4E); acc2 += s_;
        s_ = DPPF(acc3, 0x4E); acc3 += s_;

        float tg = (kc == 0) ? acc0 : (kc == 1) ? acc1 : (kc == 2) ? acc2 : acc3;
        tg += bias;
        const bool  isg = (kc == 2);
        const float arg = isg ? (tg + tg) : tg;
        const float sf  = 1.f / (1.f + __expf(-arg));
        const float act = isg ? (sf + sf - 1.f) : sf;

        const float gi = DPPF(act, 0x00);
        const float gf = DPPF(act, 0x55);
        const float gg = DPPF(act, 0xAA);
        const float go = DPPF(act, 0xFF);
        c = fmaf(gf, c, gi * gg);
        const float hnew = go * tanh_f(c);

        if (kc == 0) hh[bh ^ 1][j] = (_Float16)hnew;

        float p = hnew * wfc;
        p += DPPF(p, 0x124);
        p += DPPF(p, 0x128);
        p = xor32_add(p);
        pend_p  = p;
        pend_id = id;

        lds_barrier();
    }

    if (fc_lane && (unsigned)pend_id < (unsigned)P_)
        atomicAdd(&sums_lds[pend_id * O_ + kc], pend_p);
    if (tid == 0 && (unsigned)pend_id < (unsigned)P_)
        atomicAdd(&counts_lds[pend_id], 1.f);
    __syncthreads();

    float* sums_g = sums + (size_t)b * P_ * O_;
    for (int i = tid; i < P_ * O_; i += 512) sums_g[i] = sums_lds[i];
    float* cnt_g = counts + (size_t)b * P_;
    for (int i = tid; i < P_; i += 512) cnt_g[i] = counts_lds[i];
}

// out[b,p,o] = (sums[b,p,o] + cnt*b_fc[o]) / max(cnt,1)
__global__ void finalize_kernel(const float* __restrict__ sums,
                                const float* __restrict__ counts,
                                const float* __restrict__ b_fc,
                                float* __restrict__ out)
{
    const int idx = blockIdx.x * blockDim.x + threadIdx.x;
    if (idx >= B_ * P_ * O_) return;
    const int o  = idx % O_;
    const int bp = idx / O_;
    const float cnt = counts[bp];
    const float denom = (cnt > 0.f) ? cnt : 1.f;
    out[idx] = (sums[idx] + cnt * b_fc[o]) / denom;
}

extern "C" void kernel_launch(void* const* d_in, const int* in_sizes, int n_in,
                              void* d_out, int out_size, void* d_ws, size_t ws_size,
                              hipStream_t stream) {
    const float* x    = (const float*)d_in[0];
    const float* W_ih = (const float*)d_in[1];
    const float* W_hh = (const float*)d_in[2];
    const float* b_ih = (const float*)d_in[3];
    const float* b_hh = (const float*)d_in[4];
    const float* W_fc = (const float*)d_in[5];
    const float* b_fc = (const float*)d_in[6];

    float* out    = (float*)d_out;
    float* sums   = (float*)d_ws;                 // 384 KB @ 0
    float* counts = sums + (size_t)B_ * P_ * O_;  // 128 KB @ 384K
    // ids @ 512K (512 KB), xg @ 1M (268.4 MB)
    const size_t ids_off = 524288;
    const size_t xg_off  = 1048576;
    const size_t need    = xg_off + (size_t)B_ * R_ * T_ * sizeof(_Float16);

    if (ws_size >= need) {
        u16*      ids = (u16*)((char*)d_ws + ids_off);
        _Float16* xg  = (_Float16*)((char*)d_ws + xg_off);
        xg_precompute<<<B_ * (T_ / 64), 256, 0, stream>>>(x, W_ih, b_ih, b_hh,
                                                          xg, ids);
        lstm_fused_xg<<<B_, 512, 0, stream>>>(xg, ids, W_hh, W_fc, sums, counts);
    } else {
        lstm_fused_fb<<<B_, 512, 0, stream>>>(x, W_ih, W_hh, b_ih, b_hh, W_fc,
                                              sums, counts);
    }

    const int n = B_ * P_ * O_;
    finalize_kernel<<<(n + 255) / 256, 256, 0, stream>>>(sums, counts, b_fc, out);
}